// Round 7
// baseline (86.567 us; speedup 1.0000x reference)
//
#include <hip/hip_runtime.h>
#include <stdint.h>

// LIF scan, chunk-parallel with warm-up convergence.
// v' = fma(v, 0.95, I); s = sigmoid(10(v'-1)); hard = v'>1; v'' = v'*(1-s)
// Outputs (f32, concat): spikes[B*L], hard_latency[B], soft_latency[B]
//
// R7: revert R6's double-buffer (32KB LDS halved residency 8->5 blocks/CU and
//     regressed). Back to R4's single 16KB in-place buffer + vmcnt(0), keep
//     R6's NT drain stores, and NCHUNK 16->32: grid 4096 -> 16 queued/CU,
//     10 resident (LDS-limited) -> TLP covers the load-wait instead of
//     intra-wave pipelining. Warm re-reads are L3-hits (I is L3-resident:
//     FETCH=95MB < 128MB input in R6).

constexpr float TH_   = 1.0f;
constexpr float LEAK  = 0.95f;                   // 1 - 1/tau
constexpr float KL2E  = 14.426950408889634f;     // K * log2(e)
constexpr int   LDIM   = 4096;
constexpr int   TILE_T = 64;                     // timesteps per LDS tile
constexpr int   CH     = TILE_T / 4;             // 16 float4 chunks per row
constexpr int   NCHUNK = 32;                     // time-parallel chunks
constexpr int   WARM   = 128;                    // warm-up steps

typedef __attribute__((address_space(1))) const unsigned int glob_u32;
typedef __attribute__((address_space(3))) unsigned int lds_u32;
typedef float __attribute__((ext_vector_type(4))) f32x4;   // NT-store-compatible

__device__ __forceinline__ float exp2_fast(float x) {
#if __has_builtin(__builtin_amdgcn_exp2f)
  return __builtin_amdgcn_exp2f(x);
#else
  return exp2f(x);
#endif
}

// One LIF step. Returns surrogate s; updates v (and latf when LAT).
template <bool LAT>
__device__ __forceinline__ float lif_step(float& v, float Iv, float tf, float& latf) {
  v = fmaf(v, LEAK, Iv);                       // Euler, fused
  float e = exp2_fast(fmaf(-KL2E, v, KL2E));   // exp(-K*(v-TH)) in exp2 domain
  float s = __builtin_amdgcn_rcpf(1.0f + e);   // sigmoid
  if (LAT) {
    if (v > TH_) latf = fminf(latf, tf);       // first hard crossing (pre-reset v)
  }
  v = fmaf(-s, v, v);                          // v *= (1 - s)
  return s;
}

// ---- 64 rows x 64 cols tile, float4-chunk XOR swizzle ----
// LDS: float4 buf[64*16]; linear slot (r*16+p) holds logical chunk p^(r&15)
// of row r. global_load_lds writes slots linearly (base + lane*16B), so the
// per-lane GLOBAL address is pre-swizzled to match (rule #21: both sides).

__device__ __forceinline__ void stage_tile(const float* __restrict__ I, float4* buf,
                                           int row0, int t0, int lane) {
  const int sub = lane >> 4;                   // 0..3
  const int p   = lane & 15;                   // slot position within row
#pragma unroll
  for (int i = 0; i < CH; ++i) {
    const int r = 4 * i + sub;                 // row this lane's slot belongs to
    const int c = p ^ (r & 15);                // logical chunk stored at position p
    const float* src = I + (size_t)(row0 + r) * LDIM + t0 + 4 * c;
    __builtin_amdgcn_global_load_lds((glob_u32*)src, (lds_u32*)(buf + i * 64),
                                     16, 0, 0);   // 64 lanes x 16B -> 1KB slab
  }
}

__device__ __forceinline__ void drain_tile(const float4* buf, float* __restrict__ gOut,
                                           int lane) {
  const int c     = lane & 15;
  const int rbase = lane >> 4;
#pragma unroll
  for (int i = 0; i < CH; ++i) {
    const int r = 4 * i + rbase;
    float4 vd = buf[r * CH + (c ^ (r & 15))];  // swizzled ds_read_b128
    f32x4 w = {vd.x, vd.y, vd.z, vd.w};
    __builtin_nontemporal_store(w,
        reinterpret_cast<f32x4*>(gOut + (size_t)r * LDIM + 4 * c));  // 256B/row, NT
  }
}

// In-place: reads I group j+1 (prefetch), writes S group j back to the same
// buffer. Per-lane the read pointer is one slot ahead of the write pointer.
template <bool LAT>
__device__ __forceinline__ void process_tile(float4* __restrict__ buf, int lane,
                                             float& v, float& latf,
                                             float& ss, float& sst, float& tf) {
  const int m    = lane & 15;
  const int base = lane * CH;
  float4 c = buf[base + (0 ^ m)];
#pragma unroll
  for (int j = 0; j < CH; ++j) {
    float4 Ij = c;
    if (j + 1 < CH) c = buf[base + ((j + 1) ^ m)];
    float4 S;
    S.x = lif_step<LAT>(v, Ij.x, tf + 0.0f, latf);
    S.y = lif_step<LAT>(v, Ij.y, tf + 1.0f, latf);
    S.z = lif_step<LAT>(v, Ij.z, tf + 2.0f, latf);
    S.w = lif_step<LAT>(v, Ij.w, tf + 3.0f, latf);
    float g = (S.x + S.y) + (S.z + S.w);       // Σ s over the 4 steps
    ss += g;
    sst = fmaf(g, tf, sst);                    // Σ s·t decomposition
    sst += S.y;
    sst = fmaf(2.0f, S.z, sst);
    sst = fmaf(3.0f, S.w, sst);
    tf += 4.0f;
    buf[base + (j ^ m)] = S;                   // in-place S write
  }
}

__device__ __forceinline__ void process_warm(const float4* __restrict__ buf, int lane,
                                             float& v) {
  const int m    = lane & 15;
  const int base = lane * CH;
  float dummy = 0.0f;
  float4 c = buf[base + (0 ^ m)];
#pragma unroll
  for (int j = 0; j < CH; ++j) {
    float4 Ij = c;
    if (j + 1 < CH) c = buf[base + ((j + 1) ^ m)];
    lif_step<false>(v, Ij.x, 0.0f, dummy);
    lif_step<false>(v, Ij.y, 0.0f, dummy);
    lif_step<false>(v, Ij.z, 0.0f, dummy);
    lif_step<false>(v, Ij.w, 0.0f, dummy);
  }
}

// DIRECT=false: per-(chunk,row) partials into pA(Σs)/pB(Σs·t)/pL(first-t).
// DIRECT=true : single-chunk fallback; pA<-soft, pL<-hard directly.
template <bool DIRECT>
__global__ void __launch_bounds__(64) lif_scan(
    const float* __restrict__ I, float* __restrict__ spikes,
    float* __restrict__ pA, float* __restrict__ pB, float* __restrict__ pL,
    int B, int own, int warm) {
  __shared__ float4 buf[64 * CH];    // 16 KiB, in-place I -> S

  const int lane  = threadIdx.x;
  const int row0  = blockIdx.x * 64;
  const int row   = row0 + lane;
  const int chunk = blockIdx.y;

  const int t_own  = chunk * own;
  const int t_beg  = (chunk == 0) ? 0 : t_own - warm;
  const int nwarm  = (t_own - t_beg) / TILE_T;
  const int ntile  = nwarm + own / TILE_T;

  float v = 0.0f;
  float latf = (float)LDIM;
  float ss = 0.0f, sst = 0.0f;
  float tf = (float)t_own;           // absolute step index for owned region

  stage_tile(I, buf, row0, t_beg, lane);

  for (int k = 0; k < ntile; ++k) {
    asm volatile("s_waitcnt vmcnt(0)" ::: "memory");   // tile k landed in LDS

    if (k < nwarm) {
      process_warm(buf, lane, v);
    } else {
      const bool need_lat = !__all(latf < (float)LDIM);
      if (need_lat) process_tile<true >(buf, lane, v, latf, ss, sst, tf);
      else          process_tile<false>(buf, lane, v, latf, ss, sst, tf);
      drain_tile(buf, spikes + (size_t)row0 * LDIM + t_beg + k * TILE_T, lane);
    }

    // All LDS reads of tile k have executed; safe to restage same buffer.
    // Single wave per block -> no barrier needed.
    if (k + 1 < ntile)
      stage_tile(I, buf, row0, t_beg + (k + 1) * TILE_T, lane);
  }

  if (DIRECT) {
    pL[row] = latf;
    pA[row] = sst / (ss + 1e-6f);
  } else {
    const size_t o = (size_t)chunk * B + row;
    pA[o] = ss;
    pB[o] = sst;
    pL[o] = latf;
  }
}

extern "C" __global__ void __launch_bounds__(256) lif_reduce(
    const float* __restrict__ pA, const float* __restrict__ pB,
    const float* __restrict__ pL, float* __restrict__ hard,
    float* __restrict__ soft, int B) {
  const int r = blockIdx.x * 256 + threadIdx.x;
  if (r >= B) return;
  float a = 0.0f, b = 0.0f, l = (float)LDIM;
  for (int c = 0; c < NCHUNK; ++c) {
    a += pA[(size_t)c * B + r];
    b += pB[(size_t)c * B + r];
    l = fminf(l, pL[(size_t)c * B + r]);
  }
  hard[r] = l;
  soft[r] = b / (a + 1e-6f);
}

extern "C" void kernel_launch(void* const* d_in, const int* in_sizes, int n_in,
                              void* d_out, int out_size, void* d_ws, size_t ws_size,
                              hipStream_t stream) {
  const float* I = (const float*)d_in[0];
  const int B = in_sizes[0] / LDIM;            // 8192
  float* out    = (float*)d_out;
  float* spikes = out;
  float* hard   = out + (size_t)B * LDIM;
  float* soft   = hard + B;

  const size_t need = (size_t)3 * NCHUNK * B * sizeof(float);
  if (ws_size >= need) {
    float* pA = (float*)d_ws;
    float* pB = pA + (size_t)NCHUNK * B;
    float* pL = pB + (size_t)NCHUNK * B;
    hipLaunchKernelGGL((lif_scan<false>), dim3(B / 64, NCHUNK), dim3(64), 0, stream,
                       I, spikes, pA, pB, pL, B, LDIM / NCHUNK, WARM);
    hipLaunchKernelGGL(lif_reduce, dim3((B + 255) / 256), dim3(256), 0, stream,
                       pA, pB, pL, hard, soft, B);
  } else {
    // fallback: single chunk, direct outputs (hard<-pL, soft<-pA)
    hipLaunchKernelGGL((lif_scan<true>), dim3(B / 64, 1), dim3(64), 0, stream,
                       I, spikes, soft, soft, hard, B, LDIM, 0);
  }
}

// Round 8
// 72.252 us; speedup vs baseline: 1.1981x; 1.1981x over previous
//
#include <hip/hip_runtime.h>
#include <stdint.h>

// LIF scan, chunk-parallel with warm-up convergence.
// v' = fma(v, 0.95, I); s = sigmoid(10(v'-1)); hard = v'>1; v'' = v'*(1-s)
// Outputs (f32, concat): spikes[B*L], hard_latency[B], soft_latency[B]
//
// R8: triple-buffered HALF-tiles (3 x 8KB = 24KB -> 6 blocks/CU) with exact
//     counted vmcnt. Next tile's h0 is staged a full tile ahead, h1 staged
//     after drain; drain reads both halves so 256B/row NT stores survive.
//     Breaks R4/R7's convoy (stage -> vmcnt(0) -> compute serialization with
//     HBM idle during lockstep compute). NCHUNK=16 (warm fraction 33%).

constexpr float TH_   = 1.0f;
constexpr float LEAK  = 0.95f;                   // 1 - 1/tau
constexpr float KL2E  = 14.426950408889634f;     // K * log2(e)
constexpr int   LDIM   = 4096;
constexpr int   TILE_T = 64;                     // timesteps per (drain) tile
constexpr int   HALF_T = 32;                     // timesteps per LDS half-tile
constexpr int   CH_H   = HALF_T / 4;             // 8 float4 chunks per row-half
constexpr int   NCHUNK = 16;                     // time-parallel chunks
constexpr int   WARM   = 128;                    // warm-up steps

typedef __attribute__((address_space(1))) const unsigned int glob_u32;
typedef __attribute__((address_space(3))) unsigned int lds_u32;
typedef float __attribute__((ext_vector_type(4))) f32x4;   // NT-store-compatible

__device__ __forceinline__ float exp2_fast(float x) {
#if __has_builtin(__builtin_amdgcn_exp2f)
  return __builtin_amdgcn_exp2f(x);
#else
  return exp2f(x);
#endif
}

// One LIF step. Returns surrogate s; updates v (and latf when LAT).
template <bool LAT>
__device__ __forceinline__ float lif_step(float& v, float Iv, float tf, float& latf) {
  v = fmaf(v, LEAK, Iv);                       // Euler, fused
  float e = exp2_fast(fmaf(-KL2E, v, KL2E));   // exp(-K*(v-TH)) in exp2 domain
  float s = __builtin_amdgcn_rcpf(1.0f + e);   // sigmoid
  if (LAT) {
    if (v > TH_) latf = fminf(latf, tf);       // first hard crossing (pre-reset v)
  }
  v = fmaf(-s, v, v);                          // v *= (1 - s)
  return s;
}

// ---- half-tile: 64 rows x 32 cols, float4-chunk XOR swizzle ----
// Region: float4 reg[64*8]; row r at reg[r*8 + p]; position p holds logical
// chunk p ^ (r&7). Slab i (1KB, written by one global_load_lds x 64 lanes,
// lane-linear) = rows 8i..8i+7; lane -> (row_off=lane>>3, p=lane&7), and
// (8i+row_off)&7 == row_off, so the pre-swizzled source chunk is
// (lane&7)^(lane>>3), independent of i (rule #21: linear dest, swz source).

__device__ __forceinline__ void stage_half(const float* __restrict__ I, float4* reg,
                                           int row0, int t0, int lane) {
  const int sub = lane >> 3;                   // 0..7  (row within slab)
  const int c   = (lane & 7) ^ sub;            // pre-swizzled chunk
  const float* src0 = I + (size_t)(row0 + sub) * LDIM + t0 + 4 * c;
#pragma unroll
  for (int i = 0; i < 8; ++i) {
    __builtin_amdgcn_global_load_lds((glob_u32*)(src0 + (size_t)8 * i * LDIM),
                                     (lds_u32*)(reg + i * 64), 16, 0, 0);
  }
}

// Drain one 64-step tile (halves in regA/regB) -> 256B/row NT stores.
__device__ __forceinline__ void drain_tile(const float4* regA, const float4* regB,
                                           float* __restrict__ gOut, int lane) {
  const int c     = lane & 15;                 // chunk 0..15 of the 64t row
  const int rbase = lane >> 4;                 // 0..3
#pragma unroll
  for (int i = 0; i < 16; ++i) {
    const int r = 4 * i + rbase;
    float4 vd = (c < 8) ? regA[r * CH_H + (c ^ (r & 7))]
                        : regB[r * CH_H + ((c - 8) ^ (r & 7))];
    f32x4 w = {vd.x, vd.y, vd.z, vd.w};
    __builtin_nontemporal_store(w,
        reinterpret_cast<f32x4*>(gOut + (size_t)r * LDIM + 4 * c));  // 256B/row
  }
}

// Process one half (32 steps). In-place: reads chunk j+1, overwrites j with S.
template <bool LAT>
__device__ __forceinline__ void process_half(float4* __restrict__ reg, int lane,
                                             float& v, float& latf,
                                             float& ss, float& sst, float& tf) {
  const int m    = lane & 7;
  const int base = lane * CH_H;
  float4 c = reg[base + (0 ^ m)];
#pragma unroll
  for (int j = 0; j < CH_H; ++j) {
    float4 Ij = c;
    if (j + 1 < CH_H) c = reg[base + ((j + 1) ^ m)];
    float4 S;
    S.x = lif_step<LAT>(v, Ij.x, tf + 0.0f, latf);
    S.y = lif_step<LAT>(v, Ij.y, tf + 1.0f, latf);
    S.z = lif_step<LAT>(v, Ij.z, tf + 2.0f, latf);
    S.w = lif_step<LAT>(v, Ij.w, tf + 3.0f, latf);
    float g = (S.x + S.y) + (S.z + S.w);
    ss += g;
    sst = fmaf(g, tf, sst);
    sst += S.y;
    sst = fmaf(2.0f, S.z, sst);
    sst = fmaf(3.0f, S.w, sst);
    tf += 4.0f;
    reg[base + (j ^ m)] = S;                   // in-place S write
  }
}

__device__ __forceinline__ void warm_half(const float4* __restrict__ reg, int lane,
                                          float& v) {
  const int m    = lane & 7;
  const int base = lane * CH_H;
  float dummy = 0.0f;
  float4 c = reg[base + (0 ^ m)];
#pragma unroll
  for (int j = 0; j < CH_H; ++j) {
    float4 Ij = c;
    if (j + 1 < CH_H) c = reg[base + ((j + 1) ^ m)];
    lif_step<false>(v, Ij.x, 0.0f, dummy);
    lif_step<false>(v, Ij.y, 0.0f, dummy);
    lif_step<false>(v, Ij.z, 0.0f, dummy);
    lif_step<false>(v, Ij.w, 0.0f, dummy);
  }
}

// DIRECT=false: per-(chunk,row) partials into pA(Σs)/pB(Σs·t)/pL(first-t).
// DIRECT=true : single-chunk fallback; pA<-soft, pL<-hard directly.
template <bool DIRECT>
__global__ void __launch_bounds__(64) lif_scan(
    const float* __restrict__ I, float* __restrict__ spikes,
    float* __restrict__ pA, float* __restrict__ pB, float* __restrict__ pL,
    int B, int own, int warm) {
  __shared__ float4 lds[3][64 * CH_H];   // 3 x 8 KiB rotating half-tile regions

  const int lane  = threadIdx.x;
  const int row0  = blockIdx.x * 64;
  const int row   = row0 + lane;
  const int chunk = blockIdx.y;

  const int t_own  = chunk * own;
  const int t_beg  = (chunk == 0) ? 0 : t_own - warm;
  const int nwarm  = (t_own - t_beg) / TILE_T;     // warm tiles (64t each)
  const int ntile  = nwarm + own / TILE_T;

  float v = 0.0f;
  float latf = (float)LDIM;
  float ss = 0.0f, sst = 0.0f;
  float tf = (float)t_own;

  float4* A = lds[0];   // holds I(k, h0)
  float4* Bf = lds[1];  // holds I(k, h1)
  float4* C = lds[2];   // free; receives I(k+1, h0)

  // Prologue: [L h0(8)] [L h1(8)]  — matches the warm/k==0 wait constants.
  stage_half(I, A,  row0, t_beg,          lane);
  stage_half(I, Bf, row0, t_beg + HALF_T, lane);

  for (int k = 0; k < ntile; ++k) {
    const int t0   = t_beg + k * TILE_T;
    const bool last = (k + 1 == ntile);

    if (!last)
      stage_half(I, C, row0, t0 + TILE_T, lane);   // stage1: next h0 (8 loads)

    // wait-h0: exact counted vmcnt (in-order retirement).
    //   steady own (prev tile drained): newer = 16 NT stores + 8 + 8 = 32
    //   prev warm / prologue:           newer = 8 + 8            = 16
    //   last tile (no stage1):          newer = 16 stores + 8    = 24
    if (last)                asm volatile("s_waitcnt vmcnt(24)" ::: "memory");
    else if (k - 1 < nwarm)  asm volatile("s_waitcnt vmcnt(16)" ::: "memory");
    else                     asm volatile("s_waitcnt vmcnt(32)" ::: "memory");

    const bool is_warm = (k < nwarm);
    bool need_lat = false;
    if (is_warm) {
      warm_half(A, lane, v);
    } else {
      need_lat = !__all(latf < (float)LDIM);
      if (need_lat) process_half<true >(A, lane, v, latf, ss, sst, tf);
      else          process_half<false>(A, lane, v, latf, ss, sst, tf);
    }

    // wait-h1: newer = stage1's 8 loads (or 0 at the last tile).
    if (last) asm volatile("s_waitcnt vmcnt(0)" ::: "memory");
    else      asm volatile("s_waitcnt vmcnt(8)" ::: "memory");

    if (is_warm) {
      warm_half(Bf, lane, v);
    } else {
      if (need_lat) process_half<true >(Bf, lane, v, latf, ss, sst, tf);
      else          process_half<false>(Bf, lane, v, latf, ss, sst, tf);
      drain_tile(A, Bf, spikes + (size_t)row0 * LDIM + t0, lane);  // 16 NT stores
    }

    if (!last)
      stage_half(I, A, row0, t0 + TILE_T + HALF_T, lane);  // stage2: next h1

    // Rotate (A,B,C) -> (C,A,B): newA=C (next h0), newB=A (next h1), newC=B.
    float4* tmp = A; A = C; C = Bf; Bf = tmp;
  }

  if (DIRECT) {
    pL[row] = latf;
    pA[row] = sst / (ss + 1e-6f);
  } else {
    const size_t o = (size_t)chunk * B + row;
    pA[o] = ss;
    pB[o] = sst;
    pL[o] = latf;
  }
}

extern "C" __global__ void __launch_bounds__(256) lif_reduce(
    const float* __restrict__ pA, const float* __restrict__ pB,
    const float* __restrict__ pL, float* __restrict__ hard,
    float* __restrict__ soft, int B) {
  const int r = blockIdx.x * 256 + threadIdx.x;
  if (r >= B) return;
  float a = 0.0f, b = 0.0f, l = (float)LDIM;
  for (int c = 0; c < NCHUNK; ++c) {
    a += pA[(size_t)c * B + r];
    b += pB[(size_t)c * B + r];
    l = fminf(l, pL[(size_t)c * B + r]);
  }
  hard[r] = l;
  soft[r] = b / (a + 1e-6f);
}

extern "C" void kernel_launch(void* const* d_in, const int* in_sizes, int n_in,
                              void* d_out, int out_size, void* d_ws, size_t ws_size,
                              hipStream_t stream) {
  const float* I = (const float*)d_in[0];
  const int B = in_sizes[0] / LDIM;            // 8192
  float* out    = (float*)d_out;
  float* spikes = out;
  float* hard   = out + (size_t)B * LDIM;
  float* soft   = hard + B;

  const size_t need = (size_t)3 * NCHUNK * B * sizeof(float);
  if (ws_size >= need) {
    float* pA = (float*)d_ws;
    float* pB = pA + (size_t)NCHUNK * B;
    float* pL = pB + (size_t)NCHUNK * B;
    hipLaunchKernelGGL((lif_scan<false>), dim3(B / 64, NCHUNK), dim3(64), 0, stream,
                       I, spikes, pA, pB, pL, B, LDIM / NCHUNK, WARM);
    hipLaunchKernelGGL(lif_reduce, dim3((B + 255) / 256), dim3(256), 0, stream,
                       pA, pB, pL, hard, soft, B);
  } else {
    // fallback: single chunk, direct outputs (hard<-pL, soft<-pA)
    hipLaunchKernelGGL((lif_scan<true>), dim3(B / 64, 1), dim3(64), 0, stream,
                       I, spikes, soft, soft, hard, B, LDIM, 0);
  }
}

// Round 9
// 60.412 us; speedup vs baseline: 1.4329x; 1.1960x over previous
//
#include <hip/hip_runtime.h>
#include <stdint.h>

// LIF scan, chunk-parallel with warm-up convergence.
// v' = fma(v, 0.95, I); s = sigmoid(10(v'-1)); hard = v'>1; v'' = v'*(1-s)
// Outputs (f32, concat): spikes[B*L], hard_latency[B], soft_latency[B]
//
// R9: two row-groups per wave (lane owns rowA=row0+lane, rowB=row0+64+lane).
//     Two 16KB tiles alternate: wait/compute/drain/stage A, then B. Each
//     stage gets a full other-group compute+drain of latency cover, with
//     EXACT counted vmcnt (R6 over-waited = serialized; R8 under-waited =
//     racy no-op; neither actually tested pipelining). Tiles stay 64-step:
//     256B-row NT stores, 2-way-free LDS swizzle (no R8 8-way conflicts).

constexpr float TH_   = 1.0f;
constexpr float LEAK  = 0.95f;                   // 1 - 1/tau
constexpr float KL2E  = 14.426950408889634f;     // K * log2(e)
constexpr int   LDIM   = 4096;
constexpr int   TILE_T = 64;                     // timesteps per tile
constexpr int   CH     = TILE_T / 4;             // 16 float4 chunks per row
constexpr int   NCHUNK = 16;                     // time-parallel chunks
constexpr int   WARM   = 128;                    // warm-up steps (do not shrink:
                                                 // 256->128 already cost 0.004->8 absmax)

typedef __attribute__((address_space(1))) const unsigned int glob_u32;
typedef __attribute__((address_space(3))) unsigned int lds_u32;
typedef float __attribute__((ext_vector_type(4))) f32x4;   // NT-store-compatible

__device__ __forceinline__ float exp2_fast(float x) {
#if __has_builtin(__builtin_amdgcn_exp2f)
  return __builtin_amdgcn_exp2f(x);
#else
  return exp2f(x);
#endif
}

template <bool LAT>
__device__ __forceinline__ float lif_step(float& v, float Iv, float tf, float& latf) {
  v = fmaf(v, LEAK, Iv);                       // Euler, fused
  float e = exp2_fast(fmaf(-KL2E, v, KL2E));   // exp(-K*(v-TH)) in exp2 domain
  float s = __builtin_amdgcn_rcpf(1.0f + e);   // sigmoid
  if (LAT) {
    if (v > TH_) latf = fminf(latf, tf);       // first hard crossing (pre-reset v)
  }
  v = fmaf(-s, v, v);                          // v *= (1 - s)
  return s;
}

// ---- 64 rows x 64 cols tile, float4-chunk XOR swizzle (R4-proven) ----
// LDS: float4 buf[64*16]; linear slot (r*16+p) holds logical chunk p^(r&15).
// global_load_lds dest is lane-linear; per-lane GLOBAL src is pre-swizzled.

__device__ __forceinline__ void stage_tile(const float* __restrict__ I, float4* buf,
                                           int rowbase, int t0, int lane) {
  const int sub = lane >> 4;                   // 0..3
  const int p   = lane & 15;
#pragma unroll
  for (int i = 0; i < CH; ++i) {
    const int r = 4 * i + sub;
    const int c = p ^ (r & 15);
    const float* src = I + (size_t)(rowbase + r) * LDIM + t0 + 4 * c;
    __builtin_amdgcn_global_load_lds((glob_u32*)src, (lds_u32*)(buf + i * 64),
                                     16, 0, 0);   // 64 lanes x 16B -> 1KB slab
  }
}

__device__ __forceinline__ void drain_tile(const float4* buf, float* __restrict__ gOut,
                                           int lane) {
  const int c     = lane & 15;
  const int rbase = lane >> 4;
#pragma unroll
  for (int i = 0; i < CH; ++i) {
    const int r = 4 * i + rbase;
    float4 vd = buf[r * CH + (c ^ (r & 15))];  // swizzled ds_read_b128, 2-way free
    f32x4 w = {vd.x, vd.y, vd.z, vd.w};
    __builtin_nontemporal_store(w,
        reinterpret_cast<f32x4*>(gOut + (size_t)r * LDIM + 4 * c));  // 256B/row, NT
  }
}

// In-place: reads I chunk j+1 (prefetch), overwrites chunk j with S.
template <bool LAT>
__device__ __forceinline__ void process_tile(float4* __restrict__ buf, int lane,
                                             float& v, float& latf,
                                             float& ss, float& sst, float& tf) {
  const int m    = lane & 15;
  const int base = lane * CH;
  float4 c = buf[base + (0 ^ m)];
#pragma unroll
  for (int j = 0; j < CH; ++j) {
    float4 Ij = c;
    if (j + 1 < CH) c = buf[base + ((j + 1) ^ m)];
    float4 S;
    S.x = lif_step<LAT>(v, Ij.x, tf + 0.0f, latf);
    S.y = lif_step<LAT>(v, Ij.y, tf + 1.0f, latf);
    S.z = lif_step<LAT>(v, Ij.z, tf + 2.0f, latf);
    S.w = lif_step<LAT>(v, Ij.w, tf + 3.0f, latf);
    float g = (S.x + S.y) + (S.z + S.w);
    ss += g;
    sst = fmaf(g, tf, sst);
    sst += S.y;
    sst = fmaf(2.0f, S.z, sst);
    sst = fmaf(3.0f, S.w, sst);
    tf += 4.0f;
    buf[base + (j ^ m)] = S;                   // in-place S write
  }
}

__device__ __forceinline__ void warm_tile(const float4* __restrict__ buf, int lane,
                                          float& v) {
  const int m    = lane & 15;
  const int base = lane * CH;
  float dummy = 0.0f;
  float4 c = buf[base + (0 ^ m)];
#pragma unroll
  for (int j = 0; j < CH; ++j) {
    float4 Ij = c;
    if (j + 1 < CH) c = buf[base + ((j + 1) ^ m)];
    lif_step<false>(v, Ij.x, 0.0f, dummy);
    lif_step<false>(v, Ij.y, 0.0f, dummy);
    lif_step<false>(v, Ij.z, 0.0f, dummy);
    lif_step<false>(v, Ij.w, 0.0f, dummy);
  }
}

__device__ __forceinline__ void wait_vm(int n) {
  // n is compile-time-ish (small set); emit exact literal immediates.
  if (n >= 32)      asm volatile("s_waitcnt vmcnt(32)" ::: "memory");
  else if (n >= 16) asm volatile("s_waitcnt vmcnt(16)" ::: "memory");
  else              asm volatile("s_waitcnt vmcnt(0)"  ::: "memory");
}

// One group's phase: wait (exact), compute/warm, drain (own), stage next.
template <bool DIRECT>
__global__ void __launch_bounds__(64) lif_scan(
    const float* __restrict__ I, float* __restrict__ spikes,
    float* __restrict__ pA, float* __restrict__ pB, float* __restrict__ pL,
    int B, int own, int warm) {
  __shared__ float4 lds[2][64 * CH];   // A,B tiles: 2 x 16 KiB

  const int lane  = threadIdx.x;
  const int row0  = blockIdx.x * 128;  // block covers 128 rows (2 groups of 64)
  const int chunk = blockIdx.y;

  const int t_own = chunk * own;
  const int t_beg = (chunk == 0) ? 0 : t_own - warm;
  const int nwarm = (t_own - t_beg) / TILE_T;
  const int ntile = nwarm + own / TILE_T;

  float vA = 0.0f, vB = 0.0f;
  float latA = (float)LDIM, latB = (float)LDIM;
  float ssA = 0.0f, sstA = 0.0f, tfA = (float)t_own;
  float ssB = 0.0f, sstB = 0.0f, tfB = (float)t_own;

  // Prologue: stage A(tile0), B(tile0).
  stage_tile(I, lds[0], row0,      t_beg, lane);
  stage_tile(I, lds[1], row0 + 64, t_beg, lane);

  for (int k = 0; k < ntile; ++k) {
    const int  t0       = t_beg + k * TILE_T;
    const bool is_warm  = (k < nwarm);
    const bool prev_own = (k > 0) && (k - 1 >= nwarm);
    const bool has_next = (k + 1 < ntile);

    // ---- group A ----
    // newer-than-stageA(k): drainB(k-1) [16 if prev_own] + stageB(k) [16]
    wait_vm(prev_own ? 32 : 16);
    if (is_warm) {
      warm_tile(lds[0], lane, vA);
    } else {
      if (!__all(latA < (float)LDIM))
        process_tile<true >(lds[0], lane, vA, latA, ssA, sstA, tfA);
      else
        process_tile<false>(lds[0], lane, vA, latA, ssA, sstA, tfA);
      drain_tile(lds[0], spikes + (size_t)row0 * LDIM + t0, lane);  // 16 NT st
    }
    __builtin_amdgcn_sched_barrier(0);           // keep drain reads before restage
    if (has_next)
      stage_tile(I, lds[0], row0, t0 + TILE_T, lane);

    // ---- group B ----
    // newer-than-stageB(k): drainA(k) [16 if own] + stageA(k+1) [16 if has_next]
    wait_vm((is_warm ? 0 : 16) + (has_next ? 16 : 0));
    if (is_warm) {
      warm_tile(lds[1], lane, vB);
    } else {
      if (!__all(latB < (float)LDIM))
        process_tile<true >(lds[1], lane, vB, latB, ssB, sstB, tfB);
      else
        process_tile<false>(lds[1], lane, vB, latB, ssB, sstB, tfB);
      drain_tile(lds[1], spikes + (size_t)(row0 + 64) * LDIM + t0, lane);
    }
    __builtin_amdgcn_sched_barrier(0);
    if (has_next)
      stage_tile(I, lds[1], row0 + 64, t0 + TILE_T, lane);
  }

  const int rowA = row0 + lane, rowB = row0 + 64 + lane;
  if (DIRECT) {
    pL[rowA] = latA;                 pL[rowB] = latB;
    pA[rowA] = sstA / (ssA + 1e-6f); pA[rowB] = sstB / (ssB + 1e-6f);
  } else {
    const size_t oA = (size_t)chunk * B + rowA;
    const size_t oB = (size_t)chunk * B + rowB;
    pA[oA] = ssA;  pB[oA] = sstA;  pL[oA] = latA;
    pA[oB] = ssB;  pB[oB] = sstB;  pL[oB] = latB;
  }
}

extern "C" __global__ void __launch_bounds__(256) lif_reduce(
    const float* __restrict__ pA, const float* __restrict__ pB,
    const float* __restrict__ pL, float* __restrict__ hard,
    float* __restrict__ soft, int B) {
  const int r = blockIdx.x * 256 + threadIdx.x;
  if (r >= B) return;
  float a = 0.0f, b = 0.0f, l = (float)LDIM;
  for (int c = 0; c < NCHUNK; ++c) {
    a += pA[(size_t)c * B + r];
    b += pB[(size_t)c * B + r];
    l = fminf(l, pL[(size_t)c * B + r]);
  }
  hard[r] = l;
  soft[r] = b / (a + 1e-6f);
}

extern "C" void kernel_launch(void* const* d_in, const int* in_sizes, int n_in,
                              void* d_out, int out_size, void* d_ws, size_t ws_size,
                              hipStream_t stream) {
  const float* I = (const float*)d_in[0];
  const int B = in_sizes[0] / LDIM;            // 8192
  float* out    = (float*)d_out;
  float* spikes = out;
  float* hard   = out + (size_t)B * LDIM;
  float* soft   = hard + B;

  const size_t need = (size_t)3 * NCHUNK * B * sizeof(float);
  if (ws_size >= need) {
    float* pA = (float*)d_ws;
    float* pB = pA + (size_t)NCHUNK * B;
    float* pL = pB + (size_t)NCHUNK * B;
    hipLaunchKernelGGL((lif_scan<false>), dim3(B / 128, NCHUNK), dim3(64), 0, stream,
                       I, spikes, pA, pB, pL, B, LDIM / NCHUNK, WARM);
    hipLaunchKernelGGL(lif_reduce, dim3((B + 255) / 256), dim3(256), 0, stream,
                       pA, pB, pL, hard, soft, B);
  } else {
    // fallback: single chunk, direct outputs (hard<-pL, soft<-pA)
    hipLaunchKernelGGL((lif_scan<true>), dim3(B / 128, 1), dim3(64), 0, stream,
                       I, spikes, soft, soft, hard, B, LDIM, 0);
  }
}